// Round 3
// baseline (1115.519 us; speedup 1.0000x reference)
//
#include <hip/hip_runtime.h>

#define CLS 10000
#define BATCH 8192
#define NGRAD 100000000LL  // CLS*CLS

// Native clang vector so __builtin_nontemporal_* accepts it.
typedef float v4f __attribute__((ext_vector_type(4)));

#define ROW_BLOCKS BATCH                       // 8192 rowstats blocks
#define N4 ((NGRAD - 4) / 4)                   // 24999999 aligned float4 stores
#define COPY_PER_THREAD 4                      // 64 B per thread
#define COPY_CHUNK (256 * COPY_PER_THREAD)     // float4s per copy block
#define COPY_BLOCKS ((int)((N4 + COPY_CHUNK - 1) / COPY_CHUNK))  // 24415
#define GRID_MAIN (4 * ROW_BLOCKS + 1)         // 1:3 interleave + 1 misc block
#define NQ 10                                  // ceil(2500/256) quads per thread

// ONE dispatch, roles interleaved so the two BW streams co-schedule:
//   blk & 3 == 0 : rowstats for row b = blk>>2         (8192 blocks)
//   blk & 3 != 0 : grad copy, copyId = (blk>>2)*3+r-1  (24415 valid + 161 no-op)
//   blk == 4*ROW_BLOCKS : count copy + alignment-edge elements
__global__ __launch_bounds__(256) void fused_main(
    const float* __restrict__ x, const int* __restrict__ target,
    const float* __restrict__ matrix, const float* __restrict__ grad_state,
    const float* __restrict__ count, float* __restrict__ out,
    float* __restrict__ row_loss, float* __restrict__ row_logZ,
    int* __restrict__ row_correct)
{
  int blk = blockIdx.x;

  if (blk == 4 * ROW_BLOCKS) {
    float* out_count = out + 1 + NGRAD;  // 4B-aligned only -> scalar
    for (int c = threadIdx.x; c < CLS; c += 256) out_count[c] = count[c];
    if (threadIdx.x == 0) {
      out[1] = grad_state[0];
      out[2] = grad_state[1];
      out[3] = grad_state[2];
      out[NGRAD] = grad_state[NGRAD - 1];
    }
    return;
  }

  int r = blk & 3;
  if (r != 0) {
    // ---- grad copy: read-once/write-once -> nontemporal both sides so the
    // 800 MB stream doesn't evict matrix rows (dup-target reuse) from L2/LLC.
    long long copyId = (long long)(blk >> 2) * 3 + (r - 1);
    if (copyId >= COPY_BLOCKS) return;
    long long base = copyId * (long long)COPY_CHUNK + threadIdx.x;
    const float* src = grad_state + 3;
    v4f* dst = (v4f*)(out + 4);  // 16B aligned
#pragma unroll
    for (int j = 0; j < COPY_PER_THREAD; ++j) {
      long long k = base + (long long)j * 256;
      if (k < N4) {
        const float* s = src + 4 * k;  // 4B-aligned only -> scalar loads
        v4f v;
        v[0] = __builtin_nontemporal_load(s + 0);
        v[1] = __builtin_nontemporal_load(s + 1);
        v[2] = __builtin_nontemporal_load(s + 2);
        v[3] = __builtin_nontemporal_load(s + 3);
        __builtin_nontemporal_store(v, dst + k);
      }
    }
    return;
  }

  // ---- rowstats: one block per batch row, register-buffered two-pass ----
  // Pass 1 is pure streaming (no exp in any dependency chain): 20 back-to-back
  // 16B loads per thread -> ~10x the in-flight bytes of the online-softmax form.
  int b = blk >> 2;
  int t = target[b];
  const v4f* xr = (const v4f*)(x + (size_t)b * CLS);       // 16B aligned
  const v4f* mr = (const v4f*)(matrix + (size_t)t * CLS);

  v4f xs[NQ];
  float d0 = 0.f, d1 = 0.f, d2 = 0.f, d3 = 0.f;
  float bestv = -3.4e38f;   // thread max == argmax value
  int besti = 0x7fffffff;

#pragma unroll
  for (int k = 0; k < NQ; ++k) {
    int i = threadIdx.x + k * 256;
    if (i < CLS / 4) {
      v4f xv = __builtin_nontemporal_load(xr + i);  // x read-once: keep out of LLC
      v4f mv = mr[i];                               // matrix rows: cached
      xs[k] = xv;
      d0 += xv[0] * mv[0];
      d1 += xv[1] * mv[1];
      d2 += xv[2] * mv[2];
      d3 += xv[3] * mv[3];
#pragma unroll
      for (int j = 0; j < 4; ++j) {
        float v = xv[j];
        int idx = 4 * i + j;
        // first-occurrence argmax: strict >, ties -> lower index
        if (v > bestv || (v == bestv && idx < besti)) { bestv = v; besti = idx; }
      }
    } else {
      xs[k] = (v4f){-3.4e38f, -3.4e38f, -3.4e38f, -3.4e38f};  // exp(..-M) -> 0
    }
  }
  float dot = (d0 + d1) + (d2 + d3);

  // wave reduce: max/argmax + dot
#pragma unroll
  for (int off = 32; off > 0; off >>= 1) {
    float ov = __shfl_down(bestv, off);
    int   oi = __shfl_down(besti, off);
    float od = __shfl_down(dot, off);
    dot += od;
    if (ov > bestv || (ov == bestv && oi < besti)) { bestv = ov; besti = oi; }
  }

  __shared__ float sv[4], sd[4], ssum[4];
  __shared__ int si_[4];
  __shared__ float sM, sDot;
  __shared__ int sBest;
  int wave = threadIdx.x >> 6;
  if ((threadIdx.x & 63) == 0) { sv[wave] = bestv; si_[wave] = besti; sd[wave] = dot; }
  __syncthreads();
  if (threadIdx.x == 0) {
    for (int w = 1; w < 4; ++w) {
      dot += sd[w];
      if (sv[w] > bestv || (sv[w] == bestv && si_[w] < besti)) { bestv = sv[w]; besti = si_[w]; }
    }
    sM = bestv; sBest = besti; sDot = dot;
  }
  __syncthreads();
  float M = sM;

  // Pass 2: 40 INDEPENDENT exps over registers (no loop-carried rescale chain)
  float s0 = 0.f, s1 = 0.f, s2 = 0.f, s3 = 0.f;
#pragma unroll
  for (int k = 0; k < NQ; ++k) {
    s0 += __expf(xs[k][0] - M);
    s1 += __expf(xs[k][1] - M);
    s2 += __expf(xs[k][2] - M);
    s3 += __expf(xs[k][3] - M);
  }
  float s = (s0 + s1) + (s2 + s3);
#pragma unroll
  for (int off = 32; off > 0; off >>= 1) s += __shfl_down(s, off);
  if ((threadIdx.x & 63) == 0) ssum[wave] = s;
  __syncthreads();
  if (threadIdx.x == 0) {
    float S = ssum[0] + ssum[1] + ssum[2] + ssum[3];
    float logZ = M + __logf(S);
    row_logZ[b] = logZ;
    row_correct[b] = (sBest == t) ? 1 : 0;
    row_loss[b] = logZ - sDot;  // softlabel rows sum to 1
  }
}

// ONE epilogue dispatch:
//   block 0      : deterministic mean of row_loss -> out[0]
//   all blocks b : if pred==target, out_grad[t,:] += softmax(x[b,:]); out_count[t] += 1
__global__ __launch_bounds__(256) void fused_epilogue(
    const float* __restrict__ x, const int* __restrict__ target,
    const float* __restrict__ row_loss, const float* __restrict__ row_logZ,
    const int* __restrict__ row_correct, float* __restrict__ out)
{
  int b = blockIdx.x;

  if (b == 0) {
    float acc = 0.f;
    for (int i = threadIdx.x; i < BATCH; i += 256) acc += row_loss[i];
#pragma unroll
    for (int off = 32; off > 0; off >>= 1) acc += __shfl_down(acc, off);
    __shared__ float sw[4];
    if ((threadIdx.x & 63) == 0) sw[threadIdx.x >> 6] = acc;
    __syncthreads();
    if (threadIdx.x == 0)
      out[0] = (sw[0] + sw[1] + sw[2] + sw[3]) * (1.0f / BATCH);
  }

  if (!row_correct[b]) return;
  int t = target[b];
  float lz = row_logZ[b];
  const float* xr = x + (size_t)b * CLS;
  float* gr = out + 1 + (size_t)t * CLS;
  float* out_count = out + 1 + NGRAD;
  for (int c = threadIdx.x; c < CLS; c += 256)
    atomicAdd(&gr[c], __expf(xr[c] - lz));
  if (threadIdx.x == 0) atomicAdd(&out_count[t], 1.0f);
}

extern "C" void kernel_launch(void* const* d_in, const int* in_sizes, int n_in,
                              void* d_out, int out_size, void* d_ws, size_t ws_size,
                              hipStream_t stream)
{
  const float* x          = (const float*)d_in[0];
  const int*   target     = (const int*)d_in[1];
  const float* matrix     = (const float*)d_in[2];
  const float* grad_state = (const float*)d_in[3];
  const float* count      = (const float*)d_in[4];

  float* out = (float*)d_out;

  float* row_loss    = (float*)d_ws;                 // [BATCH]
  float* row_logZ    = row_loss + BATCH;             // [BATCH]
  int*   row_correct = (int*)(row_logZ + BATCH);     // [BATCH]

  fused_main<<<GRID_MAIN, 256, 0, stream>>>(x, target, matrix, grad_state, count,
                                            out, row_loss, row_logZ, row_correct);
  fused_epilogue<<<BATCH, 256, 0, stream>>>(x, target, row_loss, row_logZ,
                                            row_correct, out);
}